// Round 4
// baseline (536.101 us; speedup 1.0000x reference)
//
#include <hip/hip_runtime.h>
#include <stdint.h>

// CTC loss forward, MI355X.
// Phase 1 (k_gather_exp): block per (b,t) row; direct global gather of the
//   256 target emissions + blank, exp(), coalesced compact store.
// Phase 2 (k_ctc_alpha): ONE WAVE per sample; linear-domain alpha with
//   per-lane power-of-2 offsets (renorm every 4 steps, no transcendentals).
//   Emissions stream global->LDS via global_load_lds DMA in 16-row chunks,
//   double-buffered with MANUAL fine-grained s_waitcnt vmcnt(17): since the
//   block is a single wave, no __syncthreads is needed, and we never drain
//   the queue -- chunk c+1 stays in flight while chunk c is consumed
//   (prefetch distance ~16 steps ~ 1400 cyc > 900 cyc HBM latency).
//   Cross-lane shift-by-1 via DPP wave_shr1 (VALU, not DS; lane0 zero-fill
//   built in). LDS reads are ds_read_b128 (2-way bank alias = free).
// Phase 3 (k_reduce): mean over batch of nll/target_length.

#define LN2F 0.69314718055994530942f
#define NR 16  // rows per LDS chunk; vmcnt magic below assumes NR+1 == 17

#define ASYNC_CP16(g, l)                                                     \
  __builtin_amdgcn_global_load_lds(                                          \
      (__attribute__((address_space(1))) void*)(g),                          \
      (__attribute__((address_space(3))) void*)(l), 16, 0, 0)
#define ASYNC_CP4(g, l)                                                      \
  __builtin_amdgcn_global_load_lds(                                          \
      (__attribute__((address_space(1))) void*)(g),                          \
      (__attribute__((address_space(3))) void*)(l), 4, 0, 0)

// lane i <- lane i-1, lane 0 <- 0 (DPP wave_shr1, bound_ctrl=1)
__device__ __forceinline__ float shr1f(float x) {
  return __int_as_float(
      __builtin_amdgcn_update_dpp(0, __float_as_int(x), 0x138, 0xF, 0xF, true));
}
__device__ __forceinline__ int shr1i(int x) {
  return __builtin_amdgcn_update_dpp(0, x, 0x138, 0xF, 0xF, true);
}

__global__ __launch_bounds__(256) void k_gather_exp(
    const float* __restrict__ lp, const int* __restrict__ tgt,
    const int* __restrict__ ilen, float* __restrict__ El,
    float* __restrict__ Eb, int T, int V, int S) {
  const int b = blockIdx.y;
  const int t = blockIdx.x;
  if (t >= ilen[b]) return;  // phase 2 never reads t >= T_b
  const int tid = threadIdx.x;  // S == 256 == blockDim
  const int lab = tgt[b * S + tid];
  const float* row = lp + ((size_t)b * T + t) * V;
  El[((size_t)b * T + t) * S + tid] = __expf(row[lab]);
  if (tid == 0) Eb[(size_t)b * T + t] = __expf(row[0]);
}

__global__ __launch_bounds__(64) void k_ctc_alpha(
    const float* __restrict__ El, const float* __restrict__ Eb,
    const int* __restrict__ tgt, const int* __restrict__ ilen,
    const int* __restrict__ tlen, float* __restrict__ nll_out, int T, int S) {
  const int b = blockIdx.x;
  const int lane = threadIdx.x;
  const bool l0 = (lane == 0);
  __shared__ __align__(16) float elbuf[2][NR][256];
  __shared__ __align__(16) float ebbuf[2][NR];

  const int Tb = ilen[b];
  const int U = tlen[b];

  // skip flags per pair p = 4*lane + j (consume tg before any DMA issue)
  const int4 tg = *(const int4*)(tgt + (size_t)b * S + 4 * lane);
  const int tprev = __shfl_up(tg.w, 1);
  const float sk0 = (l0 || tg.x != tprev) ? 1.0f : 0.0f;
  const float sk1 = (tg.y != tg.x) ? 1.0f : 0.0f;
  const float sk2 = (tg.z != tg.y) ? 1.0f : 0.0f;
  const float sk3 = (tg.w != tg.z) ? 1.0f : 0.0f;

  const float* Elb = El + (size_t)b * T * 256;
  const float* Ebb = Eb + (size_t)b * T;
  const int lo4 = 4 * lane;

  // lane owns pairs p=4*lane..4*lane+3 (states 2p+1 label, 2p+2 blank);
  // a0 = state 0 (lane 0 only). true alpha = a * 2^o (per-lane offset).
  float a0 = 0, aL0 = 0, aL1 = 0, aL2 = 0, aL3 = 0;
  float aB0 = 0, aB1 = 0, aB2 = 0, aB3 = 0;
  int o = 0;
  float s = 1.0f;  // 2^(o_left - o)

  auto issue_chunk = [&](int c, int buf) {  // exactly NR+1 = 17 VMEM instrs
    const int base = c * NR;
#pragma unroll
    for (int r = 0; r < NR; ++r) {
      const int row = min(base + r, Tb - 1);  // clamp: dup loads are harmless
      ASYNC_CP16(Elb + ((size_t)row << 8) + lo4, &elbuf[buf][r][0]);
    }
    const int erow = min(base + (int)lane, Tb - 1);
    if (lane < NR) ASYNC_CP4(Ebb + erow, &ebbuf[buf][0]);
  };

  auto stepf = [&](float4 el, float eb) {  // generic step (t > 0)
    const float pL = shr1f(aL3) * s;        // state 2p-1 (lane0: 0 via DPP)
    float pB = shr1f(aB3) * s;              // state 2p
    pB = l0 ? a0 : pB;
    const float nB0 = (aB0 + aL0) * eb;
    const float nB1 = (aB1 + aL1) * eb;
    const float nB2 = (aB2 + aL2) * eb;
    const float nB3 = (aB3 + aL3) * eb;
    const float nL0 = (aL0 + fmaf(sk0, pL, pB)) * el.x;
    const float nL1 = (aL1 + fmaf(sk1, aL0, aB0)) * el.y;
    const float nL2 = (aL2 + fmaf(sk2, aL1, aB1)) * el.z;
    const float nL3 = (aL3 + fmaf(sk3, aL2, aB2)) * el.w;
    a0 *= eb;
    aL0 = nL0; aL1 = nL1; aL2 = nL2; aL3 = nL3;
    aB0 = nB0; aB1 = nB1; aB2 = nB2; aB3 = nB3;
  };
  auto renorm = [&]() {  // per-lane power-of-2 rescale (no transcendentals)
    float m = fmaxf(fmaxf(fmaxf(aL0, aL1), fmaxf(aL2, aL3)),
                    fmaxf(fmaxf(aB0, aB1), fmaxf(aB2, aB3)));
    m = fmaxf(m, a0);
    const bool nz = (m > 0.0f);
    const int mk = nz ? (((__float_as_int(m) >> 23) & 0xff) - 126) : 0;
    const int ocand = o + mk;
    const int oleft = shr1i(ocand);
    o = (nz || l0) ? ocand : oleft;  // zero lanes adopt left offset
    const float sc = nz ? __int_as_float((127 - mk) << 23) : 1.0f;
    aL0 *= sc; aL1 *= sc; aL2 *= sc; aL3 *= sc;
    aB0 *= sc; aB1 *= sc; aB2 *= sc; aB3 *= sc;
    a0 *= sc;
    int d = shr1i(o) - o;
    d = max(-126, min(126, d));
    s = __int_as_float((d + 127) << 23);  // 2^d
  };

  issue_chunk(0, 0);
  const int nchunks = (Tb + NR - 1) / NR;

  for (int c = 0; c < nchunks; ++c) {
    const int buf = c & 1;
    if (c + 1 < nchunks) {
      issue_chunk(c + 1, buf ^ 1);
      // outstanding = 17 (chunk c) + 17 (chunk c+1); drain the 17 oldest.
      asm volatile("s_waitcnt vmcnt(17)" ::: "memory");
    } else {
      asm volatile("s_waitcnt vmcnt(0)" ::: "memory");
    }
    const int jend = min(NR, Tb - c * NR);
    if (jend == NR) {
#pragma unroll
      for (int j = 0; j < NR; ++j) {
        const float4 el = *(const float4*)&elbuf[buf][j][lo4];
        const float eb = ebbuf[buf][j];
        if (c == 0 && j == 0) {  // t = 0 init: only states 0,1 live
          a0 = l0 ? eb : 0.0f;
          aL0 = l0 ? el.x : 0.0f;
        } else {
          stepf(el, eb);
        }
        if ((j & 3) == 3) renorm();  // t = 16c+j -> (t&3)==3 <=> (j&3)==3
      }
    } else {  // final partial chunk
      for (int j = 0; j < jend; ++j) {
        const float4 el = *(const float4*)&elbuf[buf][j][lo4];
        const float eb = ebbuf[buf][j];
        if (c == 0 && j == 0) {
          a0 = l0 ? eb : 0.0f;
          aL0 = l0 ? el.x : 0.0f;
        } else {
          stepf(el, eb);
        }
        if ((j & 3) == 3) renorm();
      }
    }
  }

  // alpha_{Tb-1} at states 2U (pair U-1 blank) and 2U-1 (pair U-1 label)
  if (lane == ((U - 1) >> 2)) {
    const int j = (U - 1) & 3;
    float sv;
    if (j == 0)      sv = aL0 + aB0;
    else if (j == 1) sv = aL1 + aB1;
    else if (j == 2) sv = aL2 + aB2;
    else             sv = aL3 + aB3;
    float nll = -LN2F * (__log2f(sv) + (float)o);
    if (!(nll < 5e29f)) nll = 0.0f;  // zero_infinity (catches NaN/inf)
    nll_out[b] = nll / (float)U;
  }
}

__global__ __launch_bounds__(64) void k_reduce(const float* __restrict__ nll,
                                               float* __restrict__ out,
                                               int B) {
  float v = 0.0f;
  for (int i = threadIdx.x; i < B; i += 64) v += nll[i];
  for (int off = 32; off > 0; off >>= 1) v += __shfl_down(v, off);
  if (threadIdx.x == 0) out[0] = v / (float)B;
}

extern "C" void kernel_launch(void* const* d_in, const int* in_sizes, int n_in,
                              void* d_out, int out_size, void* d_ws,
                              size_t ws_size, hipStream_t stream) {
  const float* lp = (const float*)d_in[0];
  const int* tgt = (const int*)d_in[1];
  const int* ilen = (const int*)d_in[2];
  const int* tlen = (const int*)d_in[3];

  const int B = in_sizes[2];
  const int S = in_sizes[1] / B;                               // 256
  const int V = 1024;                                          // fixed by problem
  const int T = (int)((size_t)in_sizes[0] / ((size_t)B * V));  // 2000

  float* El = (float*)d_ws;                 // B*T*S f32
  float* Eb = El + (size_t)B * T * S;       // B*T f32
  float* nw = Eb + (size_t)B * T;           // B f32

  dim3 g1(T, B);
  k_gather_exp<<<g1, 256, 0, stream>>>(lp, tgt, ilen, El, Eb, T, V, S);
  k_ctc_alpha<<<B, 64, 0, stream>>>(El, Eb, tgt, ilen, tlen, nw, T, S);
  k_reduce<<<1, 64, 0, stream>>>(nw, (float*)d_out, B);
}

// Round 5
// 527.217 us; speedup vs baseline: 1.0169x; 1.0169x over previous
//
#include <hip/hip_runtime.h>
#include <stdint.h>

// CTC loss forward, MI355X.
// Phase 1 (k_gather_exp): block per (b,t) row; direct global gather of the
//   256 target emissions + blank, exp(), coalesced compact store.
// Phase 2 (k_ctc_alpha): ONE WAVE per sample; linear-domain alpha with
//   per-lane power-of-2 offsets (renorm every 4 steps, no transcendentals).
//   Emissions stream global->REGISTERS in 16-row double-buffered chunks:
//   set A is consumed while set B's 17 loads are in flight (the compiler's
//   auto s_waitcnt acts as vmcnt(17); prefetch distance ~16 steps ~1400 cyc
//   > 900-cyc HBM latency). __launch_bounds__(64,1) unlocks the register
//   budget (R3's collapse to VGPR=68 was the allocator sinking the
//   pipeline); sched_barrier(0) pins load-issue before compute. Eb is one
//   lane-vector load per chunk + readlane per step (SGPR operand).
//   Cross-lane shift-by-1 via DPP wave_shr1 (VALU, lane0 zero-fill free).
// Phase 3 (k_reduce): mean over batch of nll/target_length.

#define LN2F 0.69314718055994530942f
#define NR 16  // rows per register chunk

// lane i <- lane i-1, lane 0 <- 0 (DPP wave_shr1, bound_ctrl=1)
__device__ __forceinline__ float shr1f(float x) {
  return __int_as_float(
      __builtin_amdgcn_update_dpp(0, __float_as_int(x), 0x138, 0xF, 0xF, true));
}
__device__ __forceinline__ int shr1i(int x) {
  return __builtin_amdgcn_update_dpp(0, x, 0x138, 0xF, 0xF, true);
}
__device__ __forceinline__ float rlanef(float v, int l) {
  return __int_as_float(__builtin_amdgcn_readlane(__float_as_int(v), l));
}

__global__ __launch_bounds__(256) void k_gather_exp(
    const float* __restrict__ lp, const int* __restrict__ tgt,
    const int* __restrict__ ilen, float* __restrict__ El,
    float* __restrict__ Eb, int T, int V, int S) {
  const int b = blockIdx.y;
  const int t = blockIdx.x;
  if (t >= ilen[b]) return;  // phase 2 never reads t >= T_b
  const int tid = threadIdx.x;  // S == 256 == blockDim
  const int lab = tgt[b * S + tid];
  const float* row = lp + ((size_t)b * T + t) * V;
  El[((size_t)b * T + t) * S + tid] = __expf(row[lab]);
  if (tid == 0) Eb[(size_t)b * T + t] = __expf(row[0]);
}

__global__ __launch_bounds__(64, 1) void k_ctc_alpha(
    const float* __restrict__ El, const float* __restrict__ Eb,
    const int* __restrict__ tgt, const int* __restrict__ ilen,
    const int* __restrict__ tlen, float* __restrict__ nll_out, int T, int S) {
  const int b = blockIdx.x;
  const int lane = threadIdx.x;
  const bool l0 = (lane == 0);

  const int Tb = ilen[b];
  const int U = tlen[b];

  // skip flags per pair p = 4*lane + j
  const int4 tg = *(const int4*)(tgt + (size_t)b * S + 4 * lane);
  const int tprev = __shfl_up(tg.w, 1);
  const float sk0 = (l0 || tg.x != tprev) ? 1.0f : 0.0f;
  const float sk1 = (tg.y != tg.x) ? 1.0f : 0.0f;
  const float sk2 = (tg.z != tg.y) ? 1.0f : 0.0f;
  const float sk3 = (tg.w != tg.z) ? 1.0f : 0.0f;

  const float* Elb = El + (size_t)b * T * 256;
  const float* Ebb = Eb + (size_t)b * T;
  const int lo4 = 4 * lane;

  // lane owns pairs p=4*lane..4*lane+3 (states 2p+1 label, 2p+2 blank);
  // a0 = state 0 (lane 0 only). true alpha = a * 2^o (per-lane offset).
  float a0 = 0, aL0 = 0, aL1 = 0, aL2 = 0, aL3 = 0;
  float aB0 = 0, aB1 = 0, aB2 = 0, aB3 = 0;
  int o = 0;
  float s = 1.0f;  // 2^(o_left - o)

  auto stepf = [&](float4 el, float eb) {  // generic step (t > 0)
    const float pL = shr1f(aL3) * s;        // state 2p-1 (lane0: 0 via DPP)
    float pB = shr1f(aB3) * s;              // state 2p
    pB = l0 ? a0 : pB;
    const float nB0 = (aB0 + aL0) * eb;
    const float nB1 = (aB1 + aL1) * eb;
    const float nB2 = (aB2 + aL2) * eb;
    const float nB3 = (aB3 + aL3) * eb;
    const float nL0 = (aL0 + fmaf(sk0, pL, pB)) * el.x;
    const float nL1 = (aL1 + fmaf(sk1, aL0, aB0)) * el.y;
    const float nL2 = (aL2 + fmaf(sk2, aL1, aB1)) * el.z;
    const float nL3 = (aL3 + fmaf(sk3, aL2, aB2)) * el.w;
    a0 *= eb;
    aL0 = nL0; aL1 = nL1; aL2 = nL2; aL3 = nL3;
    aB0 = nB0; aB1 = nB1; aB2 = nB2; aB3 = nB3;
  };
  auto renorm = [&]() {  // per-lane power-of-2 rescale (no transcendentals)
    float m = fmaxf(fmaxf(fmaxf(aL0, aL1), fmaxf(aL2, aL3)),
                    fmaxf(fmaxf(aB0, aB1), fmaxf(aB2, aB3)));
    m = fmaxf(m, a0);
    const bool nz = (m > 0.0f);
    const int mk = nz ? (((__float_as_int(m) >> 23) & 0xff) - 126) : 0;
    const int ocand = o + mk;
    const int oleft = shr1i(ocand);
    o = (nz || l0) ? ocand : oleft;  // zero lanes adopt left offset
    const float sc = nz ? __int_as_float((127 - mk) << 23) : 1.0f;
    aL0 *= sc; aL1 *= sc; aL2 *= sc; aL3 *= sc;
    aB0 *= sc; aB1 *= sc; aB2 *= sc; aB3 *= sc;
    a0 *= sc;
    int d = shr1i(o) - o;
    d = max(-126, min(126, d));
    s = __int_as_float((d + 127) << 23);  // 2^d
  };

  float4 elA[NR], elB[NR];
  float ebA, ebB;  // lane j holds Eb[base+j] (j < 16)

  auto load_chunk = [&](int c, float4* el, float& ebv) {  // 17 VMEM instrs
    const int base = c * NR;
    const int erow = min(base + lane, Tb - 1);
    ebv = Ebb[erow];
#pragma unroll
    for (int r = 0; r < NR; ++r) {
      const int row = min(base + r, Tb - 1);  // clamp: dup loads harmless
      el[r] = *(const float4*)(Elb + ((size_t)row << 8) + lo4);
    }
  };

  auto consume_full = [&](bool first, const float4* el, float ebv) {
#pragma unroll
    for (int j = 0; j < NR; ++j) {
      const float eb = rlanef(ebv, j);
      if (j == 0 && first) {  // t = 0 init: only states 0,1 live
        a0 = l0 ? eb : 0.0f;
        aL0 = l0 ? el[0].x : 0.0f;
      } else {
        stepf(el[j], eb);
      }
      if ((j & 3) == 3) renorm();  // t = 16c+j -> (t&3)==3 <=> (j&3)==3
    }
  };
  auto consume_tail = [&](const float4* el, float ebv, int jend) {
#pragma unroll
    for (int j = 0; j < NR; ++j) {
      if (j < jend) {
        stepf(el[j], rlanef(ebv, j));
        if ((j & 3) == 3) renorm();
      }
    }
  };

  const int nchunks = (Tb + NR - 1) / NR;  // Tb >= 1500 => nchunks >= 2
  load_chunk(0, elA, ebA);
  int c = 0;
  for (; c + 1 < nchunks; ++c) {
    if ((c & 1) == 0) {
      load_chunk(c + 1, elB, ebB);
      __builtin_amdgcn_sched_barrier(0);  // pin loads before compute
      consume_full(c == 0, elA, ebA);
    } else {
      load_chunk(c + 1, elA, ebA);
      __builtin_amdgcn_sched_barrier(0);
      consume_full(false, elB, ebB);
    }
  }
  {  // last chunk (possibly partial)
    const int jend = Tb - c * NR;
    if ((c & 1) == 0) consume_tail(elA, ebA, jend);
    else              consume_tail(elB, ebB, jend);
  }

  // alpha_{Tb-1} at states 2U (pair U-1 blank) and 2U-1 (pair U-1 label)
  if (lane == ((U - 1) >> 2)) {
    const int j = (U - 1) & 3;
    float sv;
    if (j == 0)      sv = aL0 + aB0;
    else if (j == 1) sv = aL1 + aB1;
    else if (j == 2) sv = aL2 + aB2;
    else             sv = aL3 + aB3;
    float nll = -LN2F * (__log2f(sv) + (float)o);
    if (!(nll < 5e29f)) nll = 0.0f;  // zero_infinity (catches NaN/inf)
    nll_out[b] = nll / (float)U;
  }
}

__global__ __launch_bounds__(64) void k_reduce(const float* __restrict__ nll,
                                               float* __restrict__ out,
                                               int B) {
  float v = 0.0f;
  for (int i = threadIdx.x; i < B; i += 64) v += nll[i];
  for (int off = 32; off > 0; off >>= 1) v += __shfl_down(v, off);
  if (threadIdx.x == 0) out[0] = v / (float)B;
}

extern "C" void kernel_launch(void* const* d_in, const int* in_sizes, int n_in,
                              void* d_out, int out_size, void* d_ws,
                              size_t ws_size, hipStream_t stream) {
  const float* lp = (const float*)d_in[0];
  const int* tgt = (const int*)d_in[1];
  const int* ilen = (const int*)d_in[2];
  const int* tlen = (const int*)d_in[3];

  const int B = in_sizes[2];
  const int S = in_sizes[1] / B;                               // 256
  const int V = 1024;                                          // fixed by problem
  const int T = (int)((size_t)in_sizes[0] / ((size_t)B * V));  // 2000

  float* El = (float*)d_ws;                 // B*T*S f32
  float* Eb = El + (size_t)B * T * S;       // B*T f32
  float* nw = Eb + (size_t)B * T;           // B f32

  dim3 g1(T, B);
  k_gather_exp<<<g1, 256, 0, stream>>>(lp, tgt, ilen, El, Eb, T, V, S);
  k_ctc_alpha<<<B, 64, 0, stream>>>(El, Eb, tgt, ilen, tlen, nw, T, S);
  k_reduce<<<1, 64, 0, stream>>>(nw, (float*)d_out, B);
}